// Round 3
// baseline (252.916 us; speedup 1.0000x reference)
//
#include <hip/hip_runtime.h>
#include <math.h>

#define C  2048
#define L  4096
#define L2 2048
#define CW3 6144  // C*3

// ---- d_ws layout (float offsets) ----
constexpr size_t OFF_RS_A = 0;      // 2048
constexpr size_t OFF_RQ_A = 2048;   // 2048
constexpr size_t OFF_RS_B = 4096;   // 2048
constexpr size_t OFF_RQ_B = 6144;   // 2048
constexpr size_t OFF_SCAL = 8192;   // 16: [0]=meanA [1]=coefA [2]=meanB [3]=coefB [4]=sum(fc_b)
constexpr size_t OFF_V    = 8208;   // 2048 atomic (zeroed by k1 extra blocks)
constexpr size_t OFF_O2   = 10256;  // 2048 atomic (contiguous with V)
constexpr size_t OFF_U    = 12304;  // 6144
constexpr size_t OFF_MIX  = 18448;  // 2048
// total 20496 floats = 82 KB (ws_size >= 164 KB proven)

// ---- d_out scratch (float offsets) — dead until k7 writes the real output ----
constexpr size_t CWP_OFF = 0;        // [32][2048] fc_w colsum partials
constexpr size_t GP_OFF  = 65536;    // [64][6144] G partials (conv rowgroups of 32)
constexpr size_t HP_OFF  = 458752;   // [64][6144] H partials
// end 851968 floats = 3.25 MB << 8M floats of d_out

__device__ __forceinline__ float wredf(float v) {
#pragma unroll
  for (int o = 32; o; o >>= 1) v += __shfl_down(v, o, 64);
  return v;
}
__device__ __forceinline__ double wredd(double v) {
#pragma unroll
  for (int o = 32; o; o >>= 1) v += __shfl_down(v, o, 64);
  return v;
}
__device__ __forceinline__ float sigm(float x) { return 1.f / (1.f + expf(-x)); }
__device__ __forceinline__ float simam1(float x, float m, float cf) {
  float d = x - m;
  float y = d * d * cf + 0.5f;
  return x * (1.f + 1.f / (1.f + expf(-y)));
}

// ===== k1: rowstats (2048) | fc_w colsum partials (256) | zero V/O2 (16) =====
__global__ void k1(const float* __restrict__ A, const float* __restrict__ B,
                   const float* __restrict__ fc_w, float* __restrict__ ws,
                   float* __restrict__ scr) {
  int u = blockIdx.x, tid = threadIdx.x;
  if (u < 2048) {
    __shared__ float sm[16];
    const float4* pa = (const float4*)(A + (size_t)u * L);
    const float4* pb = (const float4*)(B + (size_t)u * L);
    float sa = 0.f, qa = 0.f, sb = 0.f, qb = 0.f;
#pragma unroll
    for (int i = tid; i < L / 4; i += 256) {
      float4 va = pa[i], vb = pb[i];
      sa += (va.x + va.y) + (va.z + va.w);
      qa += (va.x * va.x + va.y * va.y) + (va.z * va.z + va.w * va.w);
      sb += (vb.x + vb.y) + (vb.z + vb.w);
      qb += (vb.x * vb.x + vb.y * vb.y) + (vb.z * vb.z + vb.w * vb.w);
    }
    sa = wredf(sa); qa = wredf(qa); sb = wredf(sb); qb = wredf(qb);
    int lane = tid & 63, wv = tid >> 6;
    if (!lane) { sm[wv] = sa; sm[4 + wv] = qa; sm[8 + wv] = sb; sm[12 + wv] = qb; }
    __syncthreads();
    if (!tid) {
      ws[OFF_RS_A + u] = sm[0] + sm[1] + sm[2] + sm[3];
      ws[OFF_RQ_A + u] = sm[4] + sm[5] + sm[6] + sm[7];
      ws[OFF_RS_B + u] = sm[8] + sm[9] + sm[10] + sm[11];
      ws[OFF_RQ_B + u] = sm[12] + sm[13] + sm[14] + sm[15];
    }
  } else if (u < 2304) {
    int cb = u - 2048;            // 0..255
    int rg = cb >> 3;             // 0..31, 64 fc_w rows each
    int col = (cb & 7) * 256 + tid;
    const float* p = fc_w + (size_t)rg * 64 * C + col;
    float acc = 0.f;
#pragma unroll 8
    for (int k = 0; k < 64; ++k) acc += p[(size_t)k * C];
    scr[CWP_OFF + (size_t)rg * 2048 + col] = acc;
  } else {
    int idx = (u - 2304) * 256 + tid;   // 0..4095 covers V then O2 (contiguous)
    ws[OFF_V + idx] = 0.f;
  }
}

// ===== k3: G/H partials with s computed inline (384) | global scalars (1) =====
__global__ void k3(const float* __restrict__ conv1_w, const float* __restrict__ fc_w,
                   const float* __restrict__ fc_b, float* __restrict__ ws,
                   float* __restrict__ scr) {
  int u = blockIdx.x, tid = threadIdx.x;
  if (u < 384) {
    __shared__ float lcw[32], ls[32];
    int rg = u / 6, cc = u % 6;      // rg 0..63 (32 conv rows each)
    int i0 = rg * 32;
    int col4 = cc * 256 + tid;       // float4 col index, 0..1535
    // phase A: s for our 32 rows (redundant across the 6 colchunks; fc_w is L3-hot)
    {
      int r = tid >> 3, g = tid & 7;  // 32 rows x 8 lanes
      const float4* wrow = (const float4*)(fc_w + (size_t)(i0 + r) * C);
      const float4* rx = (const float4*)(ws + OFF_RS_A);
      float acc = 0.f;
#pragma unroll 8
      for (int j = g; j < C / 4; j += 8) {
        float4 w = wrow[j], rv = rx[j];
        acc += w.x * rv.x + w.y * rv.y + w.z * rv.z + w.w * rv.w;
      }
      acc += __shfl_xor(acc, 1, 64);
      acc += __shfl_xor(acc, 2, 64);
      acc += __shfl_xor(acc, 4, 64);
      if (g == 0) ls[r] = 0.5f * acc + (float)L2 * fc_b[i0 + r];
    }
    if (tid < 32) {
      float a = 0.f;
#pragma unroll 8
      for (int g = 0; g < 32; ++g) a += scr[CWP_OFF + (size_t)g * 2048 + i0 + tid];
      lcw[tid] = a;
    }
    __syncthreads();
    const float4* cv = (const float4*)conv1_w;
    float4 g4 = {0.f, 0.f, 0.f, 0.f}, h4 = {0.f, 0.f, 0.f, 0.f};
#pragma unroll 8
    for (int k = 0; k < 32; ++k) {
      float4 w = cv[(size_t)(i0 + k) * 1536 + col4];
      float cwv = lcw[k], sv = ls[k];
      g4.x += cwv * w.x; g4.y += cwv * w.y; g4.z += cwv * w.z; g4.w += cwv * w.w;
      h4.x += sv * w.x;  h4.y += sv * w.y;  h4.z += sv * w.z;  h4.w += sv * w.w;
    }
    ((float4*)(scr + GP_OFF + (size_t)rg * 6144))[col4] = g4;
    ((float4*)(scr + HP_OFF + (size_t)rg * 6144))[col4] = h4;
  } else {
    // global scalars for simam (1 block)
    __shared__ double sd[5];
    int lane = tid & 63, wv = tid >> 6;
    const float* arr = ws + (wv == 0 ? OFF_RS_A : wv == 1 ? OFF_RQ_A
                                                          : wv == 2 ? OFF_RS_B : OFF_RQ_B);
    double acc = 0.0, accb = 0.0;
    for (int i = lane; i < 2048; i += 64) {
      acc += (double)arr[i];
      if (wv == 0) accb += (double)fc_b[i];
    }
    acc = wredd(acc);
    if (wv == 0) accb = wredd(accb);
    if (!lane) { sd[wv] = acc; if (wv == 0) sd[4] = accb; }
    __syncthreads();
    if (!tid) {
      const double N = (double)C * (double)L, n = N - 1.0;
      double dA = sd[1] - sd[0] * sd[0] / N;
      double dB = sd[3] - sd[2] * sd[2] / N;
      float* sc = ws + OFF_SCAL;
      sc[0] = (float)(sd[0] / N);
      sc[1] = (float)(1.0 / (4.0 * (dA / n + 1e-4)));
      sc[2] = (float)(sd[2] / N);
      sc[3] = (float)(1.0 / (4.0 * (dB / n + 1e-4)));
      sc[4] = (float)sd[4];
    }
  }
}

// ===== k4: v,o2 from raw insum (pooling fused, shuffle halo); grid 8 kb x 64 cg =====
__global__ void k4(const float* __restrict__ insum, const float* __restrict__ scr,
                   float* __restrict__ ws) {
  __shared__ float gs[96], hs[96];
  int u = blockIdx.x, tid = threadIdx.x;
  int kb = u & 7, cg = u >> 3;     // cg 0..63, 32 channels each
  int c0 = cg * 32;
  int k = kb * 256 + tid;
  int lane = tid & 63;
  if (tid < 192) {
    int t = (tid < 96) ? tid : tid - 96;
    const float* base = scr + ((tid < 96) ? GP_OFF : HP_OFF) + (size_t)c0 * 3 + t;
    float a = 0.f;
#pragma unroll 8
    for (int g = 0; g < 64; ++g) a += base[(size_t)g * 6144];
    if (tid < 96) gs[t] = a; else hs[t] = a;
  }
  __syncthreads();
  float accv = 0.f, acco = 0.f;
#pragma unroll 4
  for (int c = 0; c < 32; ++c) {
    const float* row = insum + (size_t)(c0 + c) * L;
    float2 fm = *(const float2*)(row + 2 * k);
    float xc = 0.5f * (fm.x + fm.y);
    float xl = __shfl_up(xc, 1, 64);
    float xr = __shfl_down(xc, 1, 64);
    if (lane == 0) {
      xl = 0.f;
      if (k > 0) { float2 f = *(const float2*)(row + 2 * k - 2); xl = 0.5f * (f.x + f.y); }
    }
    if (lane == 63) {
      xr = 0.f;
      if (k < L2 - 1) { float2 f = *(const float2*)(row + 2 * k + 2); xr = 0.5f * (f.x + f.y); }
    }
    accv += gs[c * 3] * xl + gs[c * 3 + 1] * xc + gs[c * 3 + 2] * xr;
    acco += hs[c * 3] * xl + hs[c * 3 + 1] * xc + hs[c * 3 + 2] * xr;
  }
  atomicAdd(ws + OFF_V + k, accv);
  atomicAdd(ws + OFF_O2 + k, acco);
}

// ===== k5: U correlations from raw input (pooling fused); v(+bias) in LDS =====
__global__ void k5(const float* __restrict__ input, float* __restrict__ ws) {
  __shared__ float vsh[2050];
  __shared__ float s12[12];
  int u = blockIdx.x, tid = threadIdx.x;
  float sb = (ws + OFF_SCAL)[4];
  if (tid == 0) { vsh[0] = 0.f; vsh[2049] = 0.f; }
  for (int j = tid; j < L2; j += 256) vsh[1 + j] = (ws + OFF_V)[j] + sb;
  __syncthreads();
  const float4* prow = (const float4*)(input + (size_t)u * L);
  float a0 = 0.f, a1 = 0.f, a2 = 0.f;
#pragma unroll
  for (int i = tid; i < L / 4; i += 256) {
    float4 f = prow[i];
    float p0 = 0.5f * (f.x + f.y), p1 = 0.5f * (f.z + f.w);
    int j = 2 * i;  // pooled index of p0; vsh[1+j] == v[j]
    a0 += p0 * vsh[j + 2] + p1 * vsh[j + 3];
    a1 += p0 * vsh[j + 1] + p1 * vsh[j + 2];
    a2 += p0 * vsh[j]     + p1 * vsh[j + 1];
  }
  a0 = wredf(a0); a1 = wredf(a1); a2 = wredf(a2);
  int lane = tid & 63, wv = tid >> 6;
  if (!lane) { s12[wv] = a0; s12[4 + wv] = a1; s12[8 + wv] = a2; }
  __syncthreads();
  if (!tid) {
    (ws + OFF_U)[u * 3 + 0] = s12[0] + s12[1] + s12[2] + s12[3];
    (ws + OFF_U)[u * 3 + 1] = s12[4] + s12[5] + s12[6] + s12[7];
    (ws + OFF_U)[u * 3 + 2] = s12[8] + s12[9] + s12[10] + s12[11];
  }
}

// ===== k6: out1 + mix =====
__global__ void k6(const float* __restrict__ conv1_w, const float* __restrict__ mix_w,
                   float* __restrict__ ws) {
  __shared__ float sl[4];
  int u = blockIdx.x, tid = threadIdx.x;
  const float4* w4p = (const float4*)(conv1_w + (size_t)u * CW3);
  const float4* u4 = (const float4*)(ws + OFF_U);
  float acc = 0.f;
#pragma unroll
  for (int m = tid; m < CW3 / 4; m += 256) {
    float4 wv = w4p[m], uv = u4[m];
    acc += wv.x * uv.x + wv.y * uv.y + wv.z * uv.z + wv.w * uv.w;
  }
  acc = wredf(acc);
  int lane = tid & 63, wv = tid >> 6;
  if (!lane) sl[wv] = acc;
  __syncthreads();
  if (!tid) {
    float mfv = sigm(mix_w[0]);
    float o1 = sigm(sl[0] + sl[1] + sl[2] + sl[3]);
    float o2 = sigm((ws + OFF_O2)[u]);
    (ws + OFF_MIX)[u] = o1 * mfv + o2 * (1.f - mfv);
  }
}

// ===== k7: per-row mid-tap gate + final elementwise (only writer of d_out) =====
__global__ void k7(const float* __restrict__ input, const float* __restrict__ insum,
                   const float* __restrict__ conv1_w, float* __restrict__ out,
                   const float* __restrict__ ws) {
  __shared__ float sl[4];
  __shared__ float shov;
  int u = blockIdx.x, tid = threadIdx.x;
  const float4* w4p = (const float4*)(conv1_w + (size_t)u * CW3);
  const float4* m4 = (const float4*)(ws + OFF_MIX);
  float acc = 0.f;
#pragma unroll
  for (int p = tid; p < 512; p += 256) {
    float4 f0 = w4p[3 * p], f1 = w4p[3 * p + 1], f2 = w4p[3 * p + 2];
    float4 m = m4[p];
    acc += f0.y * m.x + f1.x * m.y + f1.w * m.z + f2.z * m.w;
  }
  acc = wredf(acc);
  int lane = tid & 63, wv = tid >> 6;
  if (!lane) sl[wv] = acc;
  __syncthreads();
  if (!tid) shov = sigm(sl[0] + sl[1] + sl[2] + sl[3]);
  __syncthreads();
  float ovc = shov;
  const float* scal = ws + OFF_SCAL;
  float mA = scal[0], cA = scal[1], mB = scal[2], cB = scal[3];
  size_t base = (size_t)u * L;
  const float4* pa = (const float4*)(input + base);
  const float4* pb = (const float4*)(insum + base);
  float4* po = (float4*)(out + base);
#pragma unroll
  for (int i = tid; i < L / 4; i += 256) {
    float4 a = pa[i], b = pb[i], r;
    r.x = (simam1(a.x, mA, cA) * 0.6f + simam1(b.x, mB, cB) * 0.4f) * ovc;
    r.y = (simam1(a.y, mA, cA) * 0.6f + simam1(b.y, mB, cB) * 0.4f) * ovc;
    r.z = (simam1(a.z, mA, cA) * 0.6f + simam1(b.z, mB, cB) * 0.4f) * ovc;
    r.w = (simam1(a.w, mA, cA) * 0.6f + simam1(b.w, mB, cB) * 0.4f) * ovc;
    po[i] = r;
  }
}

extern "C" void kernel_launch(void* const* d_in, const int* in_sizes, int n_in,
                              void* d_out, int out_size, void* d_ws, size_t ws_size,
                              hipStream_t stream) {
  const float* input   = (const float*)d_in[0];
  const float* insum   = (const float*)d_in[1];
  const float* conv1_w = (const float*)d_in[2];
  const float* fc_w    = (const float*)d_in[3];
  const float* fc_b    = (const float*)d_in[4];
  const float* mix_w   = (const float*)d_in[5];
  float* out = (float*)d_out;
  float* ws  = (float*)d_ws;

  dim3 b(256);
  k1<<<2320, b, 0, stream>>>(input, insum, fc_w, ws, out);
  k3<<<385, b, 0, stream>>>(conv1_w, fc_w, fc_b, ws, out);
  k4<<<512, b, 0, stream>>>(insum, out, ws);
  k5<<<2048, b, 0, stream>>>(input, ws);
  k6<<<2048, b, 0, stream>>>(conv1_w, mix_w, ws);
  k7<<<2048, b, 0, stream>>>(input, insum, conv1_w, out, ws);
}

// Round 4
// 235.628 us; speedup vs baseline: 1.0734x; 1.0734x over previous
//
#include <hip/hip_runtime.h>
#include <math.h>

#define C  2048
#define L  4096
#define L2 2048
#define CW3 6144  // C*3

// ---- d_ws layout (float offsets) ----
constexpr size_t OFF_RS_A = 0;      // 2048
constexpr size_t OFF_RQ_A = 2048;   // 2048
constexpr size_t OFF_RS_B = 4096;   // 2048
constexpr size_t OFF_RQ_B = 6144;   // 2048
constexpr size_t OFF_SCAL = 8192;   // 16: [0]=meanA [1]=coefA [2]=meanB [3]=coefB [4]=sum(fc_b)
// ---- atomic region (zeroed by captured memset): floats 8208..26639 ----
constexpr size_t OFF_CW   = 8208;   // 2048  colsum(fc_w)
constexpr size_t OFF_G    = 10256;  // 6144
constexpr size_t OFF_H    = 16400;  // 6144
constexpr size_t OFF_V    = 22544;  // 2048  (no bias)
constexpr size_t OFF_O2   = 24592;  // 2048
// ---- plain ----
constexpr size_t OFF_S    = 26640;  // 2048
constexpr size_t OFF_U    = 28688;  // 6144
constexpr size_t OFF_MIX  = 34832;  // 2048
// total 36880 floats = 147.5 KB (proven ws_size >= 164 KB)

// pooled tensors staged in d_out (exactly fills it; overwritten by w7)
constexpr size_t PA_OFF = 0;         // pooled input  2048x2048
constexpr size_t PB_OFF = 4194304;   // pooled insum  2048x2048

__device__ __forceinline__ float wredf(float v) {
#pragma unroll
  for (int o = 32; o; o >>= 1) v += __shfl_down(v, o, 64);
  return v;
}
__device__ __forceinline__ double wredd(double v) {
#pragma unroll
  for (int o = 32; o; o >>= 1) v += __shfl_down(v, o, 64);
  return v;
}
__device__ __forceinline__ float sigm(float x) { return 1.f / (1.f + expf(-x)); }
__device__ __forceinline__ float simam1(float x, float m, float cf) {
  float d = x - m;
  float y = d * d * cf + 0.5f;
  return x * (1.f + 1.f / (1.f + expf(-y)));
}

// ===== w1: rowstats + pooled write (4096) | cw atomics (256) =====
__global__ void w1(const float* __restrict__ A, const float* __restrict__ B,
                   const float* __restrict__ fc_w, float* __restrict__ ws,
                   float* __restrict__ dout) {
  int u = blockIdx.x;
  int tid = threadIdx.x;
  if (u < 4096) {
    __shared__ float sm[8];
    const float* src = (u < 2048) ? A : B;
    int row = u & 2047;
    const float4* p = (const float4*)(src + (size_t)row * L);
    float4* pool = (float4*)(dout + ((u < 2048) ? PA_OFF : PB_OFF) + (size_t)row * L2);
    float s = 0.f, q = 0.f;
#pragma unroll
    for (int i = tid; i < L2 / 4; i += 256) {   // 512 float4 outputs, 2 iters
      float4 v0 = p[2 * i], v1 = p[2 * i + 1];
      s += ((v0.x + v0.y) + (v0.z + v0.w)) + ((v1.x + v1.y) + (v1.z + v1.w));
      q += (v0.x * v0.x + v0.y * v0.y) + (v0.z * v0.z + v0.w * v0.w) +
           (v1.x * v1.x + v1.y * v1.y) + (v1.z * v1.z + v1.w * v1.w);
      float4 pm;
      pm.x = (v0.x + v0.y) * 0.5f;
      pm.y = (v0.z + v0.w) * 0.5f;
      pm.z = (v1.x + v1.y) * 0.5f;
      pm.w = (v1.z + v1.w) * 0.5f;
      pool[i] = pm;
    }
    s = wredf(s); q = wredf(q);
    int lane = tid & 63, wv = tid >> 6;
    if (!lane) { sm[wv] = s; sm[4 + wv] = q; }
    __syncthreads();
    if (!tid) {
      float* rs = ws + ((u < 2048) ? OFF_RS_A : OFF_RS_B);
      float* rq = ws + ((u < 2048) ? OFF_RQ_A : OFF_RQ_B);
      rs[row] = sm[0] + sm[1] + sm[2] + sm[3];
      rq[row] = sm[4] + sm[5] + sm[6] + sm[7];
    }
  } else {
    int cb = u - 4096;            // 0..255
    int rg = cb >> 3;             // 0..31, 64 rows each
    int col = (cb & 7) * 256 + tid;
    const float* p = fc_w + (size_t)rg * 64 * C + col;
    float acc = 0.f;
#pragma unroll 8
    for (int k = 0; k < 64; ++k) acc += p[(size_t)k * C];
    atomicAdd(ws + OFF_CW + col, acc);
  }
}

// ===== w2: s vector (4 rows/block, 512 blocks) + global scalars (1 block) =====
__global__ void w2(const float* __restrict__ fc_w, const float* __restrict__ fc_b,
                   float* __restrict__ ws) {
  int u = blockIdx.x, tid = threadIdx.x;
  int lane = tid & 63, wv = tid >> 6;
  if (u < 512) {
    __shared__ float sl[16];
    int r0 = u * 4;
    const float4* rx = (const float4*)(ws + OFF_RS_A);
    const float4* w4 = (const float4*)fc_w;
    float a0 = 0.f, a1 = 0.f, a2 = 0.f, a3 = 0.f;
#pragma unroll
    for (int i = tid; i < C / 4; i += 256) {
      float4 r = rx[i];
      float4 q0 = w4[(size_t)(r0 + 0) * 512 + i];
      float4 q1 = w4[(size_t)(r0 + 1) * 512 + i];
      float4 q2 = w4[(size_t)(r0 + 2) * 512 + i];
      float4 q3 = w4[(size_t)(r0 + 3) * 512 + i];
      a0 += q0.x * r.x + q0.y * r.y + q0.z * r.z + q0.w * r.w;
      a1 += q1.x * r.x + q1.y * r.y + q1.z * r.z + q1.w * r.w;
      a2 += q2.x * r.x + q2.y * r.y + q2.z * r.z + q2.w * r.w;
      a3 += q3.x * r.x + q3.y * r.y + q3.z * r.z + q3.w * r.w;
    }
    a0 = wredf(a0); a1 = wredf(a1); a2 = wredf(a2); a3 = wredf(a3);
    if (!lane) { sl[wv] = a0; sl[4 + wv] = a1; sl[8 + wv] = a2; sl[12 + wv] = a3; }
    __syncthreads();
    if (tid < 4) {
      float s_ = sl[tid * 4 + 0] + sl[tid * 4 + 1] + sl[tid * 4 + 2] + sl[tid * 4 + 3];
      ws[OFF_S + r0 + tid] = 0.5f * s_ + (float)L2 * fc_b[r0 + tid];
    }
  } else {
    __shared__ double sd[5];
    const float* arr = ws + (wv == 0 ? OFF_RS_A : wv == 1 ? OFF_RQ_A
                                                          : wv == 2 ? OFF_RS_B : OFF_RQ_B);
    double acc = 0.0, accb = 0.0;
    for (int i = lane; i < 2048; i += 64) {
      acc += (double)arr[i];
      if (wv == 0) accb += (double)fc_b[i];
    }
    acc = wredd(acc);
    if (wv == 0) accb = wredd(accb);
    if (!lane) { sd[wv] = acc; if (wv == 0) sd[4] = accb; }
    __syncthreads();
    if (!tid) {
      const double N = (double)C * (double)L, n = N - 1.0;
      double dA = sd[1] - sd[0] * sd[0] / N;
      double dB = sd[3] - sd[2] * sd[2] / N;
      float* sc = ws + OFF_SCAL;
      sc[0] = (float)(sd[0] / N);
      sc[1] = (float)(1.0 / (4.0 * (dA / n + 1e-4)));
      sc[2] = (float)(sd[2] / N);
      sc[3] = (float)(1.0 / (4.0 * (dB / n + 1e-4)));
      sc[4] = (float)sd[4];
    }
  }
}

// ===== w3: g,h via atomics; grid 24 colchunks x 32 rowgroups = 768 =====
__global__ void w3(const float* __restrict__ conv1_w, float* __restrict__ ws) {
  __shared__ float lcw[64], ls[64];
  int u = blockIdx.x;
  int tid = threadIdx.x;
  int cc = u % 24, rg = u / 24;
  int col = cc * 256 + tid;
  int i0 = rg * 64;
  if (tid < 64) {
    lcw[tid] = (ws + OFF_CW)[i0 + tid];
    ls[tid] = (ws + OFF_S)[i0 + tid];
  }
  __syncthreads();
  const float* base = conv1_w + (size_t)i0 * CW3 + col;
  float ag = 0.f, ah = 0.f;
#pragma unroll 8
  for (int k = 0; k < 64; ++k) {
    float wv = base[(size_t)k * CW3];
    ag += lcw[k] * wv;
    ah += ls[k] * wv;
  }
  atomicAdd(ws + OFF_G + col, ag);
  atomicAdd(ws + OFF_H + col, ah);
}

// ===== w4: v,o2 from pooled insum; halo via shuffle; grid 8 kb x 64 cg = 512 =====
__global__ void w4(const float* __restrict__ dout, float* __restrict__ ws) {
  __shared__ float gs[96], hs[96];
  int u = blockIdx.x;
  int tid = threadIdx.x;
  int kb = u & 7, cg = u >> 3;   // cg 0..63, 32 channels each
  int c0 = cg * 32;
  int k = kb * 256 + tid;
  int lane = tid & 63;
  if (tid < 96) gs[tid] = (ws + OFF_G)[c0 * 3 + tid];
  else if (tid >= 128 && tid < 224) hs[tid - 128] = (ws + OFF_H)[c0 * 3 + tid - 128];
  __syncthreads();
  float accv = 0.f, acco = 0.f;
#pragma unroll 4
  for (int c = 0; c < 32; ++c) {
    const float* row = dout + PB_OFF + (size_t)(c0 + c) * L2;
    float xc = row[k];
    float xl = __shfl_up(xc, 1, 64);
    float xr = __shfl_down(xc, 1, 64);
    if (lane == 0)  xl = (k > 0) ? row[k - 1] : 0.f;
    if (lane == 63) xr = (k < L2 - 1) ? row[k + 1] : 0.f;
    accv += gs[c * 3] * xl + gs[c * 3 + 1] * xc + gs[c * 3 + 2] * xr;
    acco += hs[c * 3] * xl + hs[c * 3 + 1] * xc + hs[c * 3 + 2] * xr;
  }
  atomicAdd(ws + OFF_V + k, accv);
  atomicAdd(ws + OFF_O2 + k, acco);
}

// ===== w5: U correlations from pooled input; v (bias folded) in LDS =====
__global__ void w5(const float* __restrict__ dout, float* __restrict__ ws) {
  __shared__ float vsh[2050];
  __shared__ float s12[12];
  int u = blockIdx.x;
  int tid = threadIdx.x;
  float sb = (ws + OFF_SCAL)[4];
  if (tid == 0) { vsh[0] = 0.f; vsh[2049] = 0.f; }
  for (int j = tid; j < L2; j += 256) vsh[1 + j] = (ws + OFF_V)[j] + sb;
  __syncthreads();
  const float* prow = dout + PA_OFF + (size_t)u * L2;
  float a0 = 0.f, a1 = 0.f, a2 = 0.f;
#pragma unroll
  for (int j = tid; j < L2; j += 256) {
    float xm = prow[j];
    a0 += xm * vsh[j + 2];
    a1 += xm * vsh[j + 1];
    a2 += xm * vsh[j];
  }
  a0 = wredf(a0); a1 = wredf(a1); a2 = wredf(a2);
  int lane = tid & 63, wv = tid >> 6;
  if (!lane) { s12[wv] = a0; s12[4 + wv] = a1; s12[8 + wv] = a2; }
  __syncthreads();
  if (!tid) {
    (ws + OFF_U)[u * 3 + 0] = s12[0] + s12[1] + s12[2] + s12[3];
    (ws + OFF_U)[u * 3 + 1] = s12[4] + s12[5] + s12[6] + s12[7];
    (ws + OFF_U)[u * 3 + 2] = s12[8] + s12[9] + s12[10] + s12[11];
  }
}

// ===== w6: out1 + mix =====
__global__ void w6(const float* __restrict__ conv1_w, const float* __restrict__ mix_w,
                   float* __restrict__ ws) {
  __shared__ float sl[4];
  int u = blockIdx.x;
  int tid = threadIdx.x;
  const float4* w4p = (const float4*)(conv1_w + (size_t)u * CW3);
  const float4* u4 = (const float4*)(ws + OFF_U);
  float acc = 0.f;
#pragma unroll
  for (int m = tid; m < CW3 / 4; m += 256) {
    float4 wv = w4p[m], uv = u4[m];
    acc += wv.x * uv.x + wv.y * uv.y + wv.z * uv.z + wv.w * uv.w;
  }
  acc = wredf(acc);
  int lane = tid & 63, wv = tid >> 6;
  if (!lane) sl[wv] = acc;
  __syncthreads();
  if (!tid) {
    float mfv = sigm(mix_w[0]);
    float o1 = sigm(sl[0] + sl[1] + sl[2] + sl[3]);
    float o2 = sigm((ws + OFF_O2)[u]);
    (ws + OFF_MIX)[u] = o1 * mfv + o2 * (1.f - mfv);
  }
}

// ===== w7: per-row mid-tap gate + final elementwise (overwrites d_out) =====
__global__ void w7(const float* __restrict__ input, const float* __restrict__ insum,
                   const float* __restrict__ conv1_w, float* __restrict__ out,
                   const float* __restrict__ ws) {
  __shared__ float sl[4];
  __shared__ float shov;
  int u = blockIdx.x;
  int tid = threadIdx.x;
  const float4* w4p = (const float4*)(conv1_w + (size_t)u * CW3);
  const float4* m4 = (const float4*)(ws + OFF_MIX);
  float acc = 0.f;
#pragma unroll
  for (int p = tid; p < 512; p += 256) {
    float4 f0 = w4p[3 * p], f1 = w4p[3 * p + 1], f2 = w4p[3 * p + 2];
    float4 m = m4[p];
    acc += f0.y * m.x + f1.x * m.y + f1.w * m.z + f2.z * m.w;
  }
  acc = wredf(acc);
  int lane = tid & 63, wv = tid >> 6;
  if (!lane) sl[wv] = acc;
  __syncthreads();
  if (!tid) shov = sigm(sl[0] + sl[1] + sl[2] + sl[3]);
  __syncthreads();
  float ovc = shov;
  const float* scal = ws + OFF_SCAL;
  float mA = scal[0], cA = scal[1], mB = scal[2], cB = scal[3];
  size_t base = (size_t)u * L;
  const float4* pa = (const float4*)(input + base);
  const float4* pb = (const float4*)(insum + base);
  float4* po = (float4*)(out + base);
#pragma unroll
  for (int i = tid; i < L / 4; i += 256) {
    float4 a = pa[i], b = pb[i], r;
    r.x = (simam1(a.x, mA, cA) * 0.6f + simam1(b.x, mB, cB) * 0.4f) * ovc;
    r.y = (simam1(a.y, mA, cA) * 0.6f + simam1(b.y, mB, cB) * 0.4f) * ovc;
    r.z = (simam1(a.z, mA, cA) * 0.6f + simam1(b.z, mB, cB) * 0.4f) * ovc;
    r.w = (simam1(a.w, mA, cA) * 0.6f + simam1(b.w, mB, cB) * 0.4f) * ovc;
    po[i] = r;
  }
}

extern "C" void kernel_launch(void* const* d_in, const int* in_sizes, int n_in,
                              void* d_out, int out_size, void* d_ws, size_t ws_size,
                              hipStream_t stream) {
  const float* input   = (const float*)d_in[0];
  const float* insum   = (const float*)d_in[1];
  const float* conv1_w = (const float*)d_in[2];
  const float* fc_w    = (const float*)d_in[3];
  const float* fc_b    = (const float*)d_in[4];
  const float* mix_w   = (const float*)d_in[5];
  float* out = (float*)d_out;
  float* ws  = (float*)d_ws;

  // zero the atomic-accumulated region: CW, G, H, V, O2 (18432 floats)
  hipMemsetAsync((char*)d_ws + OFF_CW * 4, 0, 18432 * 4, stream);

  dim3 b(256);
  w1<<<4352, b, 0, stream>>>(input, insum, fc_w, ws, out);
  w2<<<513, b, 0, stream>>>(fc_w, fc_b, ws);
  w3<<<768, b, 0, stream>>>(conv1_w, ws);
  w4<<<512, b, 0, stream>>>(out, ws);
  w5<<<2048, b, 0, stream>>>(out, ws);
  w6<<<2048, b, 0, stream>>>(conv1_w, mix_w, ws);
  w7<<<2048, b, 0, stream>>>(input, insum, conv1_w, out, ws);
}